// Round 6
// baseline (124.732 us; speedup 1.0000x reference)
//
#include <hip/hip_runtime.h>

static constexpr int BATCH = 65536;
static constexpr int DDIM  = 512;
static constexpr int NCLS  = 7;
static constexpr int SLICE = NCLS * DDIM;   // 3584 floats per block partial
static constexpr int NSC   = 64;            // scalar slot spread

// Header at d_ws offset 0 (memset to 0 each launch); partials follow at +4096.
struct WS {
  double sumsq_s[NSC];
  double l1_s[NSC];
  double ce_s[NSC];
  double wcss;
  double pad;
  float  counts_s[NSC][8];
};
static_assert(sizeof(WS) <= 4096, "header must fit in 4 KB");

// Wave-uniform class accumulate: t is in an SGPR -> scalar branch tree,
// only 4 v_add_f32 execute per row instead of 7x(cmp+4 cndmask+4 add).
__device__ __forceinline__ void class_add(float4 (&acc)[NCLS], int t, const float4 f) {
  switch (t) {
    case 0: acc[0].x += f.x; acc[0].y += f.y; acc[0].z += f.z; acc[0].w += f.w; break;
    case 1: acc[1].x += f.x; acc[1].y += f.y; acc[1].z += f.z; acc[1].w += f.w; break;
    case 2: acc[2].x += f.x; acc[2].y += f.y; acc[2].z += f.z; acc[2].w += f.w; break;
    case 3: acc[3].x += f.x; acc[3].y += f.y; acc[3].z += f.z; acc[3].w += f.w; break;
    case 4: acc[4].x += f.x; acc[4].y += f.y; acc[4].z += f.z; acc[4].w += f.w; break;
    case 5: acc[5].x += f.x; acc[5].y += f.y; acc[5].z += f.z; acc[5].w += f.w; break;
    default: acc[6].x += f.x; acc[6].y += f.y; acc[6].z += f.z; acc[6].w += f.w; break;
  }
}

// Fused main pass, 512 threads = 4 row-phases x 128 float4-columns.
// RPB is a compile-time constant -> row loop fully unrollable so the scheduler
// can keep many independent 16B loads in flight (VGPR cap 128 via bounds(512,4)).
// Class sums use wave-uniform switch (lanes span columns; target is uniform
// per wave) -> minimal VALU on the consume path. Partials go out as plain
// coalesced float4 stores (no hot-path atomics).
template <int RPB>
__global__ __launch_bounds__(512, 4) void k_main(const float4* __restrict__ F,
                                                 const float4* __restrict__ A,
                                                 const int* __restrict__ tg,
                                                 const float* __restrict__ outputs,
                                                 float* __restrict__ part,
                                                 WS* __restrict__ ws) {
  const int tid  = threadIdx.x;
  const int bid  = blockIdx.x;
  const int c4   = tid & 127;   // float4 column (0..127)
  const int ph   = tid >> 7;    // row phase 0..3 (wave-uniform)
  const int slot = bid & (NSC - 1);
  const int base = bid * RPB;

  float4 acc[NCLS];
#pragma unroll
  for (int c = 0; c < NCLS; ++c) acc[c] = make_float4(0.f, 0.f, 0.f, 0.f);
  float sumsq = 0.f, l1 = 0.f;

#pragma unroll 8
  for (int k = 0; k < RPB / 8; ++k) {
    const int r = base + k * 8;
    const size_t i0 = (size_t)(r + ph) * 128 + c4;
    const float4 f0 = F[i0];
    const float4 f1 = F[i0 + 512];   // row + 4
    const float4 w0 = A[i0];
    const float4 w1 = A[i0 + 512];
    const int t0 = __builtin_amdgcn_readfirstlane(tg[r + ph]);
    const int t1 = __builtin_amdgcn_readfirstlane(tg[r + ph + 4]);

    sumsq = fmaf(f0.x, f0.x, sumsq); sumsq = fmaf(f0.y, f0.y, sumsq);
    sumsq = fmaf(f0.z, f0.z, sumsq); sumsq = fmaf(f0.w, f0.w, sumsq);
    sumsq = fmaf(f1.x, f1.x, sumsq); sumsq = fmaf(f1.y, f1.y, sumsq);
    sumsq = fmaf(f1.z, f1.z, sumsq); sumsq = fmaf(f1.w, f1.w, sumsq);
    l1 += fabsf(w0.x) + fabsf(w0.y) + fabsf(w0.z) + fabsf(w0.w) +
          fabsf(w1.x) + fabsf(w1.y) + fabsf(w1.z) + fabsf(w1.w);

    class_add(acc, t0, f0);
    class_add(acc, t1, f1);
  }

  // Fold phases 1..3 onto phase 0 via LDS (2 rounds). [..][33] = conflict-free.
  __shared__ float red[256][33];
  if (ph >= 2) {
    float* row = red[(ph - 2) * 128 + c4];
#pragma unroll
    for (int c = 0; c < NCLS; ++c) {
      row[c * 4 + 0] = acc[c].x; row[c * 4 + 1] = acc[c].y;
      row[c * 4 + 2] = acc[c].z; row[c * 4 + 3] = acc[c].w;
    }
    row[28] = sumsq; row[29] = l1;
  }
  __syncthreads();
  if (ph < 2) {
    const float* row = red[ph * 128 + c4];
#pragma unroll
    for (int c = 0; c < NCLS; ++c) {
      acc[c].x += row[c * 4 + 0]; acc[c].y += row[c * 4 + 1];
      acc[c].z += row[c * 4 + 2]; acc[c].w += row[c * 4 + 3];
    }
    sumsq += row[28]; l1 += row[29];
  }
  __syncthreads();
  if (ph == 1) {
    float* row = red[c4];
#pragma unroll
    for (int c = 0; c < NCLS; ++c) {
      row[c * 4 + 0] = acc[c].x; row[c * 4 + 1] = acc[c].y;
      row[c * 4 + 2] = acc[c].z; row[c * 4 + 3] = acc[c].w;
    }
    row[28] = sumsq; row[29] = l1;
  }
  __syncthreads();

  __shared__ float s2[2], s3[2];
  if (ph == 0) {
    const float* row = red[c4];
#pragma unroll
    for (int c = 0; c < NCLS; ++c) {
      acc[c].x += row[c * 4 + 0]; acc[c].y += row[c * 4 + 1];
      acc[c].z += row[c * 4 + 2]; acc[c].w += row[c * 4 + 3];
    }
    sumsq += row[28]; l1 += row[29];

    // Plain coalesced stores into this block's private slice. No RMW.
    float4* __restrict__ myp = reinterpret_cast<float4*>(part + (size_t)bid * SLICE);
#pragma unroll
    for (int c = 0; c < NCLS; ++c) myp[c * 128 + c4] = acc[c];

    float bs = sumsq, bl = l1;
#pragma unroll
    for (int off = 32; off > 0; off >>= 1) {
      bs += __shfl_down(bs, off);
      bl += __shfl_down(bl, off);
    }
    if ((tid & 63) == 0) { s2[tid >> 6] = bs; s3[tid >> 6] = bl; }
  }
  __syncthreads();
  if (tid == 0) {
    atomicAdd(&ws->sumsq_s[slot], (double)(s2[0] + s2[1]));
    atomicAdd(&ws->l1_s[slot],    (double)(s3[0] + s3[1]));
  }

  // CE + per-class counts over this block's rows, wave-parallel (tiny tail).
  const int lane = tid & 63, wid = tid >> 6;
  if (wid * 64 < RPB) {
    float ce = 0.f;
    float cw[NCLS];
#pragma unroll
    for (int c = 0; c < NCLS; ++c) cw[c] = 0.f;
    for (int r0 = wid * 64; r0 < RPB; r0 += 512) {
      const int r = r0 + lane;
      const bool ok = (r < RPB);
      const int row = base + (ok ? r : 0);
      const float* o = outputs + (size_t)row * NCLS;
      const float x0 = o[0], x1 = o[1], x2 = o[2], x3 = o[3],
                  x4 = o[4], x5 = o[5], x6 = o[6];
      const float m = fmaxf(fmaxf(fmaxf(x0, x1), fmaxf(x2, x3)),
                            fmaxf(fmaxf(x4, x5), x6));
      const float s = expf(x0 - m) + expf(x1 - m) + expf(x2 - m) + expf(x3 - m) +
                      expf(x4 - m) + expf(x5 - m) + expf(x6 - m);
      const int t = ok ? tg[row] : -1;
      const float xt = (t == 0) ? x0 : (t == 1) ? x1 : (t == 2) ? x2 :
                       (t == 3) ? x3 : (t == 4) ? x4 : (t == 5) ? x5 : x6;
      ce += ok ? ((m - xt) + logf(s)) : 0.f;
#pragma unroll
      for (int c = 0; c < NCLS; ++c)
        cw[c] += (float)__popcll(__ballot(t == c)) * ((lane == 0) ? 1.f : 0.f);
    }
#pragma unroll
    for (int off = 32; off > 0; off >>= 1) ce += __shfl_down(ce, off);
    if (lane == 0) {
      atomicAdd(&ws->ce_s[slot], (double)ce);
#pragma unroll
      for (int c = 0; c < NCLS; ++c) atomicAdd(&ws->counts_s[slot][c], cw[c]);
    }
  }
}

// Fold nblk private slices; compute Sum_c ||sums_c||^2 / count_c -> ws->wcss.
__global__ __launch_bounds__(256) void k_reduce(const float* __restrict__ part,
                                                WS* __restrict__ ws, int nblk) {
  const int c  = blockIdx.x >> 4;
  const int cg = blockIdx.x & 15;
  const int t  = threadIdx.x;
  const int col = cg * 32 + (t & 31);
  const int sl0 = t >> 5;   // 0..7

  float s = 0.f;
#pragma unroll 4
  for (int sl = sl0; sl < nblk; sl += 8)
    s += part[(size_t)sl * SLICE + c * DDIM + col];

  __shared__ float red[8][33];
  red[sl0][t & 31] = s;

  __shared__ float scnt;
  if (t < 64) {
    float cv = ws->counts_s[t][c];
#pragma unroll
    for (int off = 32; off > 0; off >>= 1) cv += __shfl_down(cv, off);
    if (t == 0) scnt = cv;
  }
  __syncthreads();

  if (t < 32) {
    float S = 0.f;
#pragma unroll
    for (int i = 0; i < 8; ++i) S += red[i][t];
    float q = S * S;
#pragma unroll
    for (int off = 16; off > 0; off >>= 1) q += __shfl_down(q, off);
    if (t == 0 && scnt > 0.f) atomicAdd(&ws->wcss, (double)(q / scnt));
  }
}

// Final combine: fold scalar slots, WCSS identity, write the 4 outputs.
__global__ __launch_bounds__(64) void k_fin(const WS* __restrict__ ws,
                                            float* __restrict__ out) {
  const int t = threadIdx.x;
  double a = ws->sumsq_s[t], b = ws->l1_s[t], d = ws->ce_s[t];
#pragma unroll
  for (int off = 32; off > 0; off >>= 1) {
    a += __shfl_down(a, off);
    b += __shfl_down(b, off);
    d += __shfl_down(d, off);
  }
  if (t == 0) {
    const double center = (a - ws->wcss) / (double)BATCH;
    const double ce = d / (double)BATCH;
    const double l1 = b / ((double)BATCH * (double)DDIM);
    out[0] = (float)(ce + 0.1 * center + 0.01 * l1);
    out[1] = (float)ce;
    out[2] = (float)center;
    out[3] = (float)l1;
  }
}

extern "C" void kernel_launch(void* const* d_in, const int* in_sizes, int n_in,
                              void* d_out, int out_size, void* d_ws, size_t ws_size,
                              hipStream_t stream) {
  const float*  outputs  = (const float*)d_in[0];
  const float4* features = (const float4*)d_in[1];
  const int*    targets  = (const int*)d_in[2];
  const float4* aw       = (const float4*)d_in[3];
  float* out = (float*)d_out;
  WS* ws = (WS*)d_ws;
  float* part = (float*)((char*)d_ws + 4096);

  // Largest block count whose private partials fit the workspace.
  const size_t avail = (ws_size > 4096) ? ws_size - 4096 : 0;
  int nblk = 128;
  if (avail >= (size_t)1024 * SLICE * 4) nblk = 1024;
  else if (avail >= (size_t)512 * SLICE * 4) nblk = 512;
  else if (avail >= (size_t)256 * SLICE * 4) nblk = 256;

  hipMemsetAsync(d_ws, 0, 4096, stream);

  switch (nblk) {
    case 1024: k_main<64> <<<1024, 512, 0, stream>>>(features, aw, targets, outputs, part, ws); break;
    case 512:  k_main<128><<<512,  512, 0, stream>>>(features, aw, targets, outputs, part, ws); break;
    case 256:  k_main<256><<<256,  512, 0, stream>>>(features, aw, targets, outputs, part, ws); break;
    default:   k_main<512><<<128,  512, 0, stream>>>(features, aw, targets, outputs, part, ws); break;
  }
  k_reduce<<<NCLS * 16, 256, 0, stream>>>(part, ws, nblk);
  k_fin<<<1, 64, 0, stream>>>(ws, out);
}

// Round 7
// 60.768 us; speedup vs baseline: 2.0526x; 2.0526x over previous
//
#include <hip/hip_runtime.h>

static constexpr int BATCH  = 65536;
static constexpr int DDIM   = 512;
static constexpr int NCLS   = 7;
static constexpr int SLICE  = NCLS * DDIM;      // 3584 class-sum floats
static constexpr int SLICEP = SLICE + 16;       // + 16-float scalar chunk (14400 B, 16B-aligned)
// scalar chunk layout: [0]=sumsq [1]=l1 [2]=ce [3..9]=counts[0..6]
static constexpr int NRED   = NCLS * 16;        // 112 k_reduce blocks

// Fused main pass, 512 threads = 4 row-phases x 128 float4-columns.
// R4-proven hot loop: predicated class accumulate (NO branches -> no spill),
// float4 loads, unroll 2, bounds(512,6). Everything leaves the block as plain
// coalesced stores into a private workspace slice -- no atomics, no memset.
template <int RPB>
__global__ __launch_bounds__(512, 6) void k_main(const float4* __restrict__ F,
                                                 const float4* __restrict__ A,
                                                 const int* __restrict__ tg,
                                                 const float* __restrict__ outputs,
                                                 float* __restrict__ part) {
  const int tid  = threadIdx.x;
  const int bid  = blockIdx.x;
  const int c4   = tid & 127;   // float4 column (0..127)
  const int ph   = tid >> 7;    // row phase 0..3 (wave-uniform)
  const int base = bid * RPB;

  float4 acc[NCLS];
#pragma unroll
  for (int c = 0; c < NCLS; ++c) acc[c] = make_float4(0.f, 0.f, 0.f, 0.f);
  float sumsq = 0.f, l1 = 0.f;

#pragma unroll 2
  for (int r = base; r < base + RPB; r += 8) {
    const int4 ta = *reinterpret_cast<const int4*>(tg + r);      // rows r..r+3
    const int4 tb = *reinterpret_cast<const int4*>(tg + r + 4);  // rows r+4..r+7
    const size_t i0 = (size_t)(r + ph) * 128 + c4;
    const float4 f0 = F[i0];
    const float4 f1 = F[i0 + 512];   // row + 4
    const float4 w0 = A[i0];
    const float4 w1 = A[i0 + 512];
    const int t0 = (ph == 0) ? ta.x : (ph == 1) ? ta.y : (ph == 2) ? ta.z : ta.w;
    const int t1 = (ph == 0) ? tb.x : (ph == 1) ? tb.y : (ph == 2) ? tb.z : tb.w;

    sumsq = fmaf(f0.x, f0.x, sumsq); sumsq = fmaf(f0.y, f0.y, sumsq);
    sumsq = fmaf(f0.z, f0.z, sumsq); sumsq = fmaf(f0.w, f0.w, sumsq);
    sumsq = fmaf(f1.x, f1.x, sumsq); sumsq = fmaf(f1.y, f1.y, sumsq);
    sumsq = fmaf(f1.z, f1.z, sumsq); sumsq = fmaf(f1.w, f1.w, sumsq);
    l1 += fabsf(w0.x) + fabsf(w0.y) + fabsf(w0.z) + fabsf(w0.w) +
          fabsf(w1.x) + fabsf(w1.y) + fabsf(w1.z) + fabsf(w1.w);

#pragma unroll
    for (int c = 0; c < NCLS; ++c) {
      acc[c].x += (t0 == c) ? f0.x : 0.f;
      acc[c].y += (t0 == c) ? f0.y : 0.f;
      acc[c].z += (t0 == c) ? f0.z : 0.f;
      acc[c].w += (t0 == c) ? f0.w : 0.f;
      acc[c].x += (t1 == c) ? f1.x : 0.f;
      acc[c].y += (t1 == c) ? f1.y : 0.f;
      acc[c].z += (t1 == c) ? f1.z : 0.f;
      acc[c].w += (t1 == c) ? f1.w : 0.f;
    }
  }

  // Fold phases 1..3 onto phase 0 via LDS (2 rounds). [..][33] = conflict-free.
  __shared__ float red[256][33];
  if (ph >= 2) {
    float* row = red[(ph - 2) * 128 + c4];
#pragma unroll
    for (int c = 0; c < NCLS; ++c) {
      row[c * 4 + 0] = acc[c].x; row[c * 4 + 1] = acc[c].y;
      row[c * 4 + 2] = acc[c].z; row[c * 4 + 3] = acc[c].w;
    }
    row[28] = sumsq; row[29] = l1;
  }
  __syncthreads();
  if (ph < 2) {
    const float* row = red[ph * 128 + c4];
#pragma unroll
    for (int c = 0; c < NCLS; ++c) {
      acc[c].x += row[c * 4 + 0]; acc[c].y += row[c * 4 + 1];
      acc[c].z += row[c * 4 + 2]; acc[c].w += row[c * 4 + 3];
    }
    sumsq += row[28]; l1 += row[29];
  }
  __syncthreads();
  if (ph == 1) {
    float* row = red[c4];
#pragma unroll
    for (int c = 0; c < NCLS; ++c) {
      row[c * 4 + 0] = acc[c].x; row[c * 4 + 1] = acc[c].y;
      row[c * 4 + 2] = acc[c].z; row[c * 4 + 3] = acc[c].w;
    }
    row[28] = sumsq; row[29] = l1;
  }
  __syncthreads();

  __shared__ float s2[2], s3[2];
  if (ph == 0) {
    const float* row = red[c4];
#pragma unroll
    for (int c = 0; c < NCLS; ++c) {
      acc[c].x += row[c * 4 + 0]; acc[c].y += row[c * 4 + 1];
      acc[c].z += row[c * 4 + 2]; acc[c].w += row[c * 4 + 3];
    }
    sumsq += row[28]; l1 += row[29];

    // Plain coalesced stores into this block's private slice. No RMW.
    float4* __restrict__ myp = reinterpret_cast<float4*>(part + (size_t)bid * SLICEP);
#pragma unroll
    for (int c = 0; c < NCLS; ++c) myp[c * 128 + c4] = acc[c];

    float bs = sumsq, bl = l1;
#pragma unroll
    for (int off = 32; off > 0; off >>= 1) {
      bs += __shfl_down(bs, off);
      bl += __shfl_down(bl, off);
    }
    if ((tid & 63) == 0) { s2[tid >> 6] = bs; s3[tid >> 6] = bl; }
  }

  // CE + per-class counts over this block's rows, wave-parallel.
  constexpr int NACT = (RPB / 64 < 8) ? RPB / 64 : 8;   // active waves
  __shared__ float ce_w[8];
  __shared__ float cw_w[8][8];
  const int lane = tid & 63, wid = tid >> 6;
  if (wid < NACT) {
    float ce = 0.f;
    float cw[NCLS];
#pragma unroll
    for (int c = 0; c < NCLS; ++c) cw[c] = 0.f;
    for (int r0 = wid * 64; r0 < RPB; r0 += NACT * 64) {
      const int row = base + r0 + lane;
      const float* o = outputs + (size_t)row * NCLS;
      const float x0 = o[0], x1 = o[1], x2 = o[2], x3 = o[3],
                  x4 = o[4], x5 = o[5], x6 = o[6];
      const float m = fmaxf(fmaxf(fmaxf(x0, x1), fmaxf(x2, x3)),
                            fmaxf(fmaxf(x4, x5), x6));
      const float s = expf(x0 - m) + expf(x1 - m) + expf(x2 - m) + expf(x3 - m) +
                      expf(x4 - m) + expf(x5 - m) + expf(x6 - m);
      const int t = tg[row];
      const float xt = (t == 0) ? x0 : (t == 1) ? x1 : (t == 2) ? x2 :
                       (t == 3) ? x3 : (t == 4) ? x4 : (t == 5) ? x5 : x6;
      ce += (m - xt) + logf(s);
#pragma unroll
      for (int c = 0; c < NCLS; ++c)
        cw[c] += (float)__popcll(__ballot(t == c)) * ((lane == 0) ? 1.f : 0.f);
    }
#pragma unroll
    for (int off = 32; off > 0; off >>= 1) ce += __shfl_down(ce, off);
    if (lane == 0) {
      ce_w[wid] = ce;
#pragma unroll
      for (int c = 0; c < NCLS; ++c) cw_w[wid][c] = cw[c];
    }
  }
  __syncthreads();

  if (tid == 0) {
    float ceb = 0.f, cb[NCLS];
#pragma unroll
    for (int c = 0; c < NCLS; ++c) cb[c] = 0.f;
#pragma unroll
    for (int w = 0; w < NACT; ++w) {
      ceb += ce_w[w];
#pragma unroll
      for (int c = 0; c < NCLS; ++c) cb[c] += cw_w[w][c];
    }
    float* sp = part + (size_t)bid * SLICEP + SLICE;
    sp[0] = s2[0] + s2[1];   // sumsq
    sp[1] = s3[0] + s3[1];   // l1
    sp[2] = ceb;             // ce
#pragma unroll
    for (int c = 0; c < NCLS; ++c) sp[3 + c] = cb[c];
  }
}

// Fold nblk private slices for one (class, 32-col group); write Sum_col S^2
// as one double (plain store -- nothing needs pre-zeroing).
__global__ __launch_bounds__(256) void k_reduce(const float* __restrict__ part,
                                                double* __restrict__ qpart,
                                                int nblk) {
  const int c  = blockIdx.x >> 4;
  const int cg = blockIdx.x & 15;
  const int t  = threadIdx.x;
  const int col = cg * 32 + (t & 31);
  const int sl0 = t >> 5;   // 0..7

  float s = 0.f;
#pragma unroll 4
  for (int sl = sl0; sl < nblk; sl += 8)
    s += part[(size_t)sl * SLICEP + c * DDIM + col];

  __shared__ float red[8][33];
  red[sl0][t & 31] = s;
  __syncthreads();

  if (t < 32) {
    float S = 0.f;
#pragma unroll
    for (int i = 0; i < 8; ++i) S += red[i][t];
    float q = S * S;
#pragma unroll
    for (int off = 16; off > 0; off >>= 1) q += __shfl_down(q, off);
    if (t == 0) qpart[blockIdx.x] = (double)q;
  }
}

// Finalize: fold per-slice scalars + 112 q-partials, WCSS identity, write out.
__global__ __launch_bounds__(512) void k_fin(const float* __restrict__ part,
                                             const double* __restrict__ qpart,
                                             float* __restrict__ out, int nblk) {
  const int t = threadIdx.x;
  const int lane = t & 63, wid = t >> 6;

  double ss = 0.0, l1 = 0.0, ce = 0.0;
  float cnt[NCLS];
#pragma unroll
  for (int c = 0; c < NCLS; ++c) cnt[c] = 0.f;
  for (int sl = t; sl < nblk; sl += 512) {
    const float* sp = part + (size_t)sl * SLICEP + SLICE;
    ss += (double)sp[0];
    l1 += (double)sp[1];
    ce += (double)sp[2];
#pragma unroll
    for (int c = 0; c < NCLS; ++c) cnt[c] += sp[3 + c];
  }

#pragma unroll
  for (int off = 32; off > 0; off >>= 1) {
    ss += __shfl_down(ss, off);
    l1 += __shfl_down(l1, off);
    ce += __shfl_down(ce, off);
#pragma unroll
    for (int c = 0; c < NCLS; ++c) cnt[c] += __shfl_down(cnt[c], off);
  }

  __shared__ double lss[8], ll1[8], lce[8];
  __shared__ float lcnt[8][8];
  if (lane == 0) {
    lss[wid] = ss; ll1[wid] = l1; lce[wid] = ce;
#pragma unroll
    for (int c = 0; c < NCLS; ++c) lcnt[wid][c] = cnt[c];
  }
  __syncthreads();

  __shared__ float counts_sh[NCLS];
  __shared__ double tot[3];
  if (t == 0) {
    double a = 0, b = 0, d = 0;
    float cc[NCLS];
#pragma unroll
    for (int c = 0; c < NCLS; ++c) cc[c] = 0.f;
#pragma unroll
    for (int w = 0; w < 8; ++w) {
      a += lss[w]; b += ll1[w]; d += lce[w];
#pragma unroll
      for (int c = 0; c < NCLS; ++c) cc[c] += lcnt[w][c];
    }
    tot[0] = a; tot[1] = b; tot[2] = d;
#pragma unroll
    for (int c = 0; c < NCLS; ++c) counts_sh[c] = cc[c];
  }
  __syncthreads();

  // WCSS subtrahend: threads 0..111 each own one (class, col-group) partial.
  double myq = 0.0;
  if (t < NRED) {
    const float cn = counts_sh[t >> 4];
    myq = (cn > 0.f) ? qpart[t] / (double)cn : 0.0;
  }
#pragma unroll
  for (int off = 32; off > 0; off >>= 1) myq += __shfl_down(myq, off);
  __shared__ double qs[2];
  if (lane == 0 && wid < 2) qs[wid] = myq;
  __syncthreads();

  if (t == 0) {
    const double wcss = qs[0] + qs[1];
    const double center = (tot[0] - wcss) / (double)BATCH;
    const double cem = tot[2] / (double)BATCH;
    const double l1m = tot[1] / ((double)BATCH * (double)DDIM);
    out[0] = (float)(cem + 0.1 * center + 0.01 * l1m);
    out[1] = (float)cem;
    out[2] = (float)center;
    out[3] = (float)l1m;
  }
}

extern "C" void kernel_launch(void* const* d_in, const int* in_sizes, int n_in,
                              void* d_out, int out_size, void* d_ws, size_t ws_size,
                              hipStream_t stream) {
  const float*  outputs  = (const float*)d_in[0];
  const float4* features = (const float4*)d_in[1];
  const int*    targets  = (const int*)d_in[2];
  const float4* aw       = (const float4*)d_in[3];
  float* out = (float*)d_out;
  float* part = (float*)d_ws;

  // Largest block count whose slices + q-partials fit the workspace.
  auto need = [](int nblk) { return (size_t)nblk * SLICEP * 4 + NRED * 8; };
  int nblk = 128;
  if (ws_size >= need(512)) nblk = 512;
  else if (ws_size >= need(256)) nblk = 256;
  double* qpart = (double*)((char*)d_ws + (size_t)nblk * SLICEP * 4);

  switch (nblk) {
    case 512: k_main<128><<<512, 512, 0, stream>>>(features, aw, targets, outputs, part); break;
    case 256: k_main<256><<<256, 512, 0, stream>>>(features, aw, targets, outputs, part); break;
    default:  k_main<512><<<128, 512, 0, stream>>>(features, aw, targets, outputs, part); break;
  }
  k_reduce<<<NRED, 256, 0, stream>>>(part, qpart, nblk);
  k_fin<<<1, 512, 0, stream>>>(part, qpart, out, nblk);
}